// Round 4
// baseline (244.627 us; speedup 1.0000x reference)
//
#include <hip/hip_runtime.h>

// StateSpaceLayer: out[b,t,r,c] = sum_{j<=t} A[r]^(t-j) * x[b,j,r,c]
// == linear recurrence out[t] = A[r]*out[t-1] + x[t] along seq.
// Shapes: x (4,512,64,64) f32, A (64,) f32, out (4,512,64,64) f32.
//
// V5: SINGLE-kernel decoupled chunk scan (no grid sync, no extra launches).
//   Lessons: V3 coop launch cost ~200us; V4's 3 kernels cost ~8us/gap plus
//   16 MB of extra E/C round-trips. So: one ordinary kernel.
//   Block = (b, time-chunk m, half-plane h): streams 8 contiguous 16 KB
//   planes of x, scans locally in regs, publishes its chunk-end aggregate
//   E[b,m] (release flag), batch-spins on all predecessor flags (pipelined,
//   one round trip), Horner-combines aggregates with a^8 (L2/L3-resident),
//   then fixes up and streams out. HBM: x + out + E ~= 75 MB one-pass.
//   Safety: 512 blocks x 512 thr, <=128 VGPR, LDS=0 -> all co-resident
//   (4 blocks/CU capacity, need 2); additionally blocks only wait on
//   LOWER block ids (ascending dispatch) - two independent no-deadlock nets.

#define B_     4
#define SEQ_   512
#define D_     64
#define PLANE_ (D_ * D_)            // 4096 floats = 16 KB per timestep
#define PQ_    (PLANE_ / 4)         // 1024 float4 per plane
#define CH_    8                    // timesteps per chunk
#define NCH_   (SEQ_ / CH_)         // 64 chunks
#define SPLIT_ 2                    // half-planes
#define THR_   (PQ_ / SPLIT_)       // 512 threads
#define GRID_  (B_ * NCH_ * SPLIT_) // 512 blocks
#define NFLAGS_ GRID_

__global__ __launch_bounds__(THR_, 4) void ssm_dlb(
    const float* __restrict__ x, const float* __restrict__ A,
    float* __restrict__ out, float* __restrict__ E,
    int* __restrict__ flags)
{
    const int blk = blockIdx.x;              // (b*NCH_+m)*SPLIT_ + h
    const int h   = blk & (SPLIT_ - 1);
    const int m   = (blk >> 1) & (NCH_ - 1);
    const int b   = blk >> 7;
    const int k   = h * THR_ + threadIdx.x;  // float4 slot in plane
    const int r   = k >> 4;                  // decay row of this slot

    const float a  = fmaxf(A[r], 1e-6f);     // clip like reference (EPS=1e-6)
    const float a2 = a * a, a4 = a2 * a2, aL = a4 * a4;   // a^8

    const float4* xp = (const float4*)x + (size_t)(b * SEQ_ + m * CH_) * PQ_ + k;
    float4*       op = (float4*)out     + (size_t)(b * SEQ_ + m * CH_) * PQ_ + k;

    // Phase 1: local scan of 8 contiguous planes (fully coalesced stream).
    float4 loc[CH_];
    float s0 = 0.f, s1 = 0.f, s2 = 0.f, s3 = 0.f;
#pragma unroll
    for (int t = 0; t < CH_; ++t) {
        float4 v = xp[t * PQ_];
        s0 = fmaf(s0, a, v.x);
        s1 = fmaf(s1, a, v.y);
        s2 = fmaf(s2, a, v.z);
        s3 = fmaf(s3, a, v.w);
        loc[t] = make_float4(s0, s1, s2, s3);
    }

    // Phase 2: publish chunk-end aggregate + release flag.
    // (last chunk of each batch has no consumers - skip publish)
    if (m < NCH_ - 1) {
        ((float4*)E)[(size_t)(b * NCH_ + m) * PQ_ + k] = make_float4(s0, s1, s2, s3);
        __syncthreads();                     // all block stores issued & drained
        if (threadIdx.x == 0) {
            __threadfence();                 // agent-scope release of E data
            __hip_atomic_store(&flags[blk], 1, __ATOMIC_RELEASE,
                               __HIP_MEMORY_SCOPE_AGENT);
        }
    }

    // Phase 3: batched spin on predecessor flags, then Horner over aggregates.
    float c0 = 0.f, c1 = 0.f, c2 = 0.f, c3 = 0.f;
    if (m > 0) {
        const int fbase = (b * NCH_) * SPLIT_ + h;   // flag of chunk mp: fbase + 2*mp
        for (;;) {
            int allset = 1;
            for (int mp = 0; mp < m; ++mp) {         // pipelined relaxed loads
                allset &= (__hip_atomic_load(&flags[fbase + mp * SPLIT_],
                           __ATOMIC_RELAXED, __HIP_MEMORY_SCOPE_AGENT) != 0);
            }
            if (allset) break;
            __builtin_amdgcn_s_sleep(4);
        }
        __threadfence();   // acquire side: order + invalidate stale L1 lines

        const float4* Eb = (const float4*)E + (size_t)(b * NCH_) * PQ_ + k;
        for (int mp = 0; mp < m; ++mp) {             // L2/L3-resident, pipelined
            float4 e = Eb[(size_t)mp * PQ_];
            c0 = fmaf(c0, aL, e.x);
            c1 = fmaf(c1, aL, e.y);
            c2 = fmaf(c2, aL, e.z);
            c3 = fmaf(c3, aL, e.w);
        }
    }

    // Phase 4: fixup + contiguous store.  out[j0+t] = loc[t] + carry*a^(t+1)
    float p = a;
#pragma unroll
    for (int t = 0; t < CH_; ++t) {
        float4 l = loc[t];
        op[t * PQ_] = make_float4(fmaf(c0, p, l.x), fmaf(c1, p, l.y),
                                  fmaf(c2, p, l.z), fmaf(c3, p, l.w));
        p *= a;
    }
}

// ---- Fallback (ws unusable): V1 single-kernel strided scan (proven 82.6us)
#define CHF_ 32
#define NWF_ (SEQ_ / CHF_)
__global__ __launch_bounds__(NWF_ * 64) void ssm_fallback(
    const float* __restrict__ x, const float* __restrict__ A,
    float* __restrict__ out)
{
    __shared__ float Elds[NWF_ * D_];
    const int blk = blockIdx.x, bi = blk >> 6, r = blk & 63;
    const int tid = threadIdx.x, w = tid >> 6, c = tid & 63;
    const float a = fmaxf(A[r], 1e-6f);
    const size_t base = ((size_t)(bi * SEQ_ + w * CHF_) * D_ + r) * D_ + c;
    const float* xp = x + base;
    float*       op = out + base;
    const int js = D_ * D_;
    float local[CHF_];
    float state = 0.0f;
#pragma unroll
    for (int t = 0; t < CHF_; ++t) {
        state = fmaf(state, a, xp[(size_t)t * js]);
        local[t] = state;
    }
    Elds[w * D_ + c] = state;
    __syncthreads();
    float aL = a * a; aL *= aL; aL *= aL; aL *= aL; aL *= aL;  // a^32
    float carry = 0.0f;
    for (int wp = 0; wp < w; ++wp) carry = fmaf(carry, aL, Elds[wp * D_ + c]);
    float p = a;
#pragma unroll
    for (int t = 0; t < CHF_; ++t) {
        op[(size_t)t * js] = fmaf(carry, p, local[t]);
        p *= a;
    }
}

extern "C" void kernel_launch(void* const* d_in, const int* in_sizes, int n_in,
                              void* d_out, int out_size, void* d_ws, size_t ws_size,
                              hipStream_t stream) {
    const float* x   = (const float*)d_in[0];
    const float* A   = (const float*)d_in[1];
    float*       out = (float*)d_out;

    const size_t eBytes = sizeof(float) * (size_t)B_ * NCH_ * PLANE_;  // 4 MB
    const size_t fBytes = sizeof(int) * (size_t)NFLAGS_;               // 2 KB

    if (d_ws != nullptr && ws_size >= eBytes + fBytes) {
        float* E     = (float*)d_ws;
        int*   flags = (int*)((char*)d_ws + eBytes);
        // ws is re-poisoned (nonzero) by the harness each iteration:
        // flags MUST be zeroed in-stream before the kernel.
        hipMemsetAsync(flags, 0, fBytes, stream);
        hipLaunchKernelGGL(ssm_dlb, dim3(GRID_), dim3(THR_), 0, stream,
                           x, A, out, E, flags);
    } else {
        hipLaunchKernelGGL(ssm_fallback, dim3(B_ * D_), dim3(NWF_ * 64),
                           0, stream, x, A, out);
    }
}

// Round 6
// 81.858 us; speedup vs baseline: 2.9884x; 2.9884x over previous
//
#include <hip/hip_runtime.h>

// StateSpaceLayer: out[b,t,r,c] = sum_{j<=t} A[r]^(t-j) * x[b,j,r,c]
// == linear recurrence out[t] = A[r]*out[t-1] + x[t] along seq.
// Shapes: x (4,512,64,64) f32, A (64,) f32, out (4,512,64,64) f32.
//
// V6b: V6 with the compile fix — __builtin_nontemporal_store requires a
// NATIVE vector type, not HIP's float4 class; use ext_vector_type(4).
//
// V6 theory (untested until now):
//   V5's kernel reported VGPR_Count=28, which cannot hold the loc[8]
//   float4 scan results -> the compiler re-materializes the x loads in the
//   store phase (x is __restrict__ const, so re-loading is legal). That
//   makes the kernel read x TWICE and serializes stores behind fresh
//   dependent loads. Fixes:
//     1. __launch_bounds__(1024, 1): min 1 wave/EU -> VGPR budget 512,
//        no pressure-based reason to sink loads.
//     2. asm keep-alive on every loc component after phase 1: values are
//        pinned in VGPRs, re-load impossible.
//     3. Non-temporal stores for out: write stream doesn't evict x/E from
//        per-XCD L2.
//   Cross-block carry schemes are dead ends on this problem size:
//   coop launch +200us (V3), 3-kernel gaps +8us each (V4), flag spin
//   +140us (V5). Single kernel, one pass, LDS carries.

#define B_    4
#define SEQ_  512
#define D_    64
#define CH_   8                  // timesteps per thread
#define NCH_  (SEQ_ / CH_)       // 64 chunks
#define NCQ_  (D_ / 4)           // 16 float4 columns
#define NTHR_ (NCH_ * NCQ_)      // 1024 threads per block

typedef float f32x4 __attribute__((ext_vector_type(4)));

__global__ __launch_bounds__(NTHR_, 1) void ssm_scan_kernel(
    const float* __restrict__ x, const float* __restrict__ A,
    float* __restrict__ out)
{
    __shared__ float4 Elds[NCH_][NCQ_];   // 4 KB: chunk-end states

    const int blk = blockIdx.x;          // 0 .. B_*D_-1
    const int bi  = blk >> 6;            // batch index
    const int r   = blk & 63;            // row (decay) index
    const int tid = threadIdx.x;
    const int ch  = tid >> 4;            // chunk id 0..63
    const int cq  = tid & 15;            // float4 column 0..15

    const float a = fmaxf(A[r], 1e-6f);  // clip like reference (EPS=1e-6)

    const int j0 = ch * CH_;
    // flat float index of x[bi, j0, r, cq*4]
    const size_t base = ((size_t)(bi * SEQ_ + j0) * D_ + r) * D_ + cq * 4;
    const float4* xp = (const float4*)(x + base);
    f32x4*        op = (f32x4*)(out + base);
    const int jstride4 = (D_ * D_) / 4;  // 1024 float4 between timesteps

    // Phase 1: local scan of this chunk with zero initial state.
    float4 loc[CH_];
    float s0 = 0.f, s1 = 0.f, s2 = 0.f, s3 = 0.f;
    #pragma unroll
    for (int t = 0; t < CH_; ++t) {
        float4 v = xp[(size_t)t * jstride4];
        s0 = fmaf(s0, a, v.x);
        s1 = fmaf(s1, a, v.y);
        s2 = fmaf(s2, a, v.z);
        s3 = fmaf(s3, a, v.w);
        loc[t] = make_float4(s0, s1, s2, s3);
    }

    // Pin the scan results in VGPRs: forbids the compiler from re-loading
    // x in phase 3 (which would double the x traffic and add latency
    // chains before every store).
    #pragma unroll
    for (int t = 0; t < CH_; ++t) {
        asm volatile("" : "+v"(loc[t].x), "+v"(loc[t].y),
                         "+v"(loc[t].z), "+v"(loc[t].w));
    }

    // Publish chunk-end state (last chunk has no consumers).
    if (ch < NCH_ - 1) {
        Elds[ch][cq] = make_float4(s0, s1, s2, s3);
    }
    __syncthreads();

    // a^CH_ (= a^8) via 3 squarings.
    float a2 = a * a, a4 = a2 * a2, aL = a4 * a4;

    // Carry into this chunk = scan state after chunk ch-1:
    //   S_{ch-1} = sum_{cp<ch} aL^(ch-1-cp) * E_cp   (Horner, low->high)
    // LDS reads are same-address broadcasts within each 16-lane group: free.
    float c0 = 0.f, c1 = 0.f, c2 = 0.f, c3 = 0.f;
    for (int cp = 0; cp < ch; ++cp) {
        float4 e = Elds[cp][cq];
        c0 = fmaf(c0, aL, e.x);
        c1 = fmaf(c1, aL, e.y);
        c2 = fmaf(c2, aL, e.z);
        c3 = fmaf(c3, aL, e.w);
    }

    // Phase 3: fix up with carry and store (non-temporal: out is write-once,
    // keep it out of L2 so x/E lines survive).
    float p = a;
    #pragma unroll
    for (int t = 0; t < CH_; ++t) {
        float4 l = loc[t];
        f32x4 o;
        o.x = fmaf(c0, p, l.x);
        o.y = fmaf(c1, p, l.y);
        o.z = fmaf(c2, p, l.z);
        o.w = fmaf(c3, p, l.w);
        __builtin_nontemporal_store(o, &op[(size_t)t * jstride4]);
        p *= a;
    }
}

extern "C" void kernel_launch(void* const* d_in, const int* in_sizes, int n_in,
                              void* d_out, int out_size, void* d_ws, size_t ws_size,
                              hipStream_t stream) {
    const float* x   = (const float*)d_in[0];
    const float* A   = (const float*)d_in[1];
    float*       out = (float*)d_out;

    dim3 grid(B_ * D_);            // 256 blocks, one per (batch, r)
    dim3 block(NTHR_);             // 1024 threads = 16 waves
    hipLaunchKernelGGL(ssm_scan_kernel, grid, block, 0, stream, x, A, out);
}